// Round 1
// baseline (232.895 us; speedup 1.0000x reference)
//
#include <hip/hip_runtime.h>
#include <hip/hip_bf16.h>

#define DHID 512
#define MAXP 18

// One block (256 threads = 4 waves) per token.
__global__ __launch_bounds__(256) void hs_loss_kernel(
    const float* __restrict__ h,            // (n, DHID)
    const int*   __restrict__ targets,      // (n)
    const float* __restrict__ W,            // (n_internal, DHID)
    const int*   __restrict__ path_nodes,   // (vocab, MAXP)
    const float* __restrict__ path_targets, // (vocab, MAXP)
    const float* __restrict__ path_masks,   // (vocab, MAXP)
    float* __restrict__ acc,                // [0]=loss sum, [1]=valid count
    int vocab)
{
    __shared__ float hs[DHID];
    __shared__ float wsum[4];
    __shared__ float msum[4];

    const int token = blockIdx.x;
    const int tid   = threadIdx.x;
    const int wave  = tid >> 6;
    const int lane  = tid & 63;

    // stage h row: 512 floats / 256 threads = 1 float2 each
    ((float2*)hs)[tid] = ((const float2*)(h + (size_t)token * DHID))[tid];
    __syncthreads();

    int t = targets[token];
    t = min(max(t, 0), vocab - 1);

    float local_loss = 0.f;
    float local_mask = 0.f;

    for (int step = wave; step < MAXP; step += 4) {
        const int   idx  = t * MAXP + step;
        int         node = path_nodes[idx];
        node = max(node, 0);
        const float tgt  = path_targets[idx];
        const float msk  = path_masks[idx];

        const float4* wrow = (const float4*)(W + (size_t)node * DHID);
        // lane handles 8 contiguous elems: 32 B/lane, wave covers 2 KB coalesced
        float4 w0 = wrow[lane * 2];
        float4 w1 = wrow[lane * 2 + 1];
        float4 h0 = ((const float4*)hs)[lane * 2];
        float4 h1 = ((const float4*)hs)[lane * 2 + 1];

        float d = w0.x * h0.x + w0.y * h0.y + w0.z * h0.z + w0.w * h0.w
                + w1.x * h1.x + w1.y * h1.y + w1.z * h1.z + w1.w * h1.w;

        // full 64-lane butterfly reduce
        for (int off = 32; off > 0; off >>= 1)
            d += __shfl_xor(d, off);

        if (lane == 0) {
            const float x = d;
            const float bce = fmaxf(x, 0.f) - x * tgt + log1pf(expf(-fabsf(x)));
            local_loss += bce * msk;
            local_mask += msk;
        }
    }

    if (lane == 0) { wsum[wave] = local_loss; msum[wave] = local_mask; }
    __syncthreads();

    if (tid == 0) {
        const float total = wsum[0] + wsum[1] + wsum[2] + wsum[3];
        const float m     = msum[0] + msum[1] + msum[2] + msum[3];
        atomicAdd(&acc[0], total);
        if (m > 0.f) atomicAdd(&acc[1], 1.0f);
    }
}

__global__ void hs_finalize_kernel(const float* __restrict__ acc,
                                   float* __restrict__ out)
{
    const float m = acc[1];
    const float loss = (m > 0.f) ? acc[0] / fmaxf(m, 1.f) : 0.f;
    out[0] = loss;
}

extern "C" void kernel_launch(void* const* d_in, const int* in_sizes, int n_in,
                              void* d_out, int out_size, void* d_ws, size_t ws_size,
                              hipStream_t stream) {
    const float* h            = (const float*)d_in[0];
    const int*   targets      = (const int*)d_in[1];
    const float* W            = (const float*)d_in[2];
    const int*   path_nodes   = (const int*)d_in[3];
    const float* path_targets = (const float*)d_in[4];
    const float* path_masks   = (const float*)d_in[5];
    float*       out          = (float*)d_out;

    const int n     = in_sizes[1];            // number of tokens (B*S)
    const int vocab = in_sizes[3] / MAXP;     // 50257

    float* acc = (float*)d_ws;
    hipMemsetAsync(acc, 0, 2 * sizeof(float), stream);

    hs_loss_kernel<<<n, 256, 0, stream>>>(h, targets, W, path_nodes,
                                          path_targets, path_masks, acc, vocab);
    hs_finalize_kernel<<<1, 1, 0, stream>>>(acc, out);
}

// Round 2
// 56.941 us; speedup vs baseline: 4.0901x; 4.0901x over previous
//
#include <hip/hip_runtime.h>
#include <hip/hip_bf16.h>

#define DHID 512
#define MAXP 18

// One wave (64 lanes) per token; 4 tokens per 256-thread block.
// Each lane holds 8 floats of h in registers and accumulates 18 partial dots.
// All 36 W-row float4 gathers per lane are independent -> deep MLP.
__global__ __launch_bounds__(256) void hs_loss_kernel(
    const float* __restrict__ h,            // (n, DHID)
    const int*   __restrict__ targets,      // (n)
    const float* __restrict__ W,            // (n_internal, DHID)
    const int*   __restrict__ path_nodes,   // (vocab, MAXP)
    const float* __restrict__ path_targets, // (vocab, MAXP)
    const float* __restrict__ path_masks,   // (vocab, MAXP)
    float* __restrict__ loss_part,          // (gridDim.x)
    float* __restrict__ cnt_part,           // (gridDim.x)
    int n, int vocab)
{
    const int tid  = threadIdx.x;
    const int wave = tid >> 6;
    const int lane = tid & 63;
    int token = blockIdx.x * 4 + wave;
    const bool alive = (token < n);
    if (!alive) token = n - 1;   // safe loads; contribution zeroed below

    // h row in registers: lane covers [lane*16B, ...] and [+1KB]
    const float4* h4 = (const float4*)(h + (size_t)token * DHID);
    float4 h0 = h4[lane];
    float4 h1 = h4[lane + 64];

    int t = targets[token];
    t = min(max(t, 0), vocab - 1);

    int nodes[MAXP];
    #pragma unroll
    for (int s = 0; s < MAXP; ++s)
        nodes[s] = max(path_nodes[t * MAXP + s], 0);

    float p[MAXP];
    // 3 groups of 6 steps: 12 float4 gathers in flight per lane per group
    #pragma unroll
    for (int g = 0; g < 3; ++g) {
        float4 w0[6], w1[6];
        #pragma unroll
        for (int j = 0; j < 6; ++j) {
            const float4* wr = (const float4*)(W + (size_t)nodes[g * 6 + j] * DHID);
            w0[j] = wr[lane];
            w1[j] = wr[lane + 64];
        }
        #pragma unroll
        for (int j = 0; j < 6; ++j) {
            p[g * 6 + j] = w0[j].x * h0.x + w0[j].y * h0.y + w0[j].z * h0.z + w0[j].w * h0.w
                         + w1[j].x * h1.x + w1[j].y * h1.y + w1[j].z * h1.z + w1[j].w * h1.w;
        }
    }

    // 18 independent 64-lane butterfly reductions (latency overlaps)
    #pragma unroll
    for (int s = 0; s < MAXP; ++s) {
        #pragma unroll
        for (int off = 32; off > 0; off >>= 1)
            p[s] += __shfl_xor(p[s], off);
    }

    // lanes 0..17 each finalize one path step (parallel transcendentals)
    float contrib = 0.f;
    float mval    = 0.f;
    if (lane < MAXP) {
        float x = 0.f;
        #pragma unroll
        for (int s = 0; s < MAXP; ++s)       // static select (no scratch)
            if (lane == s) x = p[s];
        const float tgt = path_targets[t * MAXP + lane];
        const float msk = path_masks[t * MAXP + lane];
        const float bce = fmaxf(x, 0.f) - x * tgt + log1pf(expf(-fabsf(x)));
        contrib = bce * msk;
        mval    = msk;
    }
    #pragma unroll
    for (int off = 32; off > 0; off >>= 1) {
        contrib += __shfl_xor(contrib, off);
        mval    += __shfl_xor(mval, off);
    }

    __shared__ float ls[4], cs[4];
    if (lane == 0) {
        ls[wave] = alive ? contrib : 0.f;
        cs[wave] = (alive && mval > 0.f) ? 1.f : 0.f;
    }
    __syncthreads();
    if (tid == 0) {
        loss_part[blockIdx.x] = ls[0] + ls[1] + ls[2] + ls[3];
        cnt_part[blockIdx.x]  = cs[0] + cs[1] + cs[2] + cs[3];
    }
}

__global__ __launch_bounds__(256) void hs_finalize_kernel(
    const float* __restrict__ loss_part,
    const float* __restrict__ cnt_part,
    float* __restrict__ out, int nblocks)
{
    __shared__ float sl[4], sc[4];
    float l = 0.f, c = 0.f;
    for (int i = threadIdx.x; i < nblocks; i += 256) {
        l += loss_part[i];
        c += cnt_part[i];
    }
    #pragma unroll
    for (int off = 32; off > 0; off >>= 1) {
        l += __shfl_xor(l, off);
        c += __shfl_xor(c, off);
    }
    const int wave = threadIdx.x >> 6;
    const int lane = threadIdx.x & 63;
    if (lane == 0) { sl[wave] = l; sc[wave] = c; }
    __syncthreads();
    if (threadIdx.x == 0) {
        const float L = sl[0] + sl[1] + sl[2] + sl[3];
        const float C = sc[0] + sc[1] + sc[2] + sc[3];
        out[0] = (C > 0.f) ? L / fmaxf(C, 1.f) : 0.f;
    }
}

extern "C" void kernel_launch(void* const* d_in, const int* in_sizes, int n_in,
                              void* d_out, int out_size, void* d_ws, size_t ws_size,
                              hipStream_t stream) {
    const float* h            = (const float*)d_in[0];
    const int*   targets      = (const int*)d_in[1];
    const float* W            = (const float*)d_in[2];
    const int*   path_nodes   = (const int*)d_in[3];
    const float* path_targets = (const float*)d_in[4];
    const float* path_masks   = (const float*)d_in[5];
    float*       out          = (float*)d_out;

    const int n     = in_sizes[1];            // tokens (B*S)
    const int vocab = in_sizes[3] / MAXP;     // 50257

    const int nblocks = (n + 3) / 4;          // 4 tokens (waves) per block
    float* loss_part = (float*)d_ws;
    float* cnt_part  = loss_part + nblocks;

    hs_loss_kernel<<<nblocks, 256, 0, stream>>>(h, targets, W, path_nodes,
                                                path_targets, path_masks,
                                                loss_part, cnt_part, n, vocab);
    hs_finalize_kernel<<<1, 256, 0, stream>>>(loss_part, cnt_part, out, nblocks);
}

// Round 3
// 46.423 us; speedup vs baseline: 5.0168x; 1.2266x over previous
//
#include <hip/hip_runtime.h>
#include <hip/hip_bf16.h>
#include <hip/hip_fp8.h>

#define DHID 512
#define MAXP 18
#define W_SCALE 64.0f
#define W_INV_SCALE (1.0f / 64.0f)

__device__ __forceinline__ float fp8tof(unsigned int b) {
    __hip_fp8_e4m3 q;
    q.__x = (__hip_fp8_storage_t)(b & 0xFFu);
    return (float)q;
}

// K1: stream-convert W fp32 -> fp8 e4m3 (scaled by 64). Pure streaming pass.
__global__ __launch_bounds__(256) void convert_w_kernel(
    const float* __restrict__ W, unsigned char* __restrict__ W8, int total)
{
    int idx = (blockIdx.x * 256 + threadIdx.x) * 8;
    const int stride = gridDim.x * 256 * 8;
    for (; idx + 7 < total; idx += stride) {
        float4 a = *(const float4*)(W + idx);
        float4 b = *(const float4*)(W + idx + 4);
        const float v[8] = {a.x, a.y, a.z, a.w, b.x, b.y, b.z, b.w};
        unsigned int lo = 0, hi = 0;
        #pragma unroll
        for (int j = 0; j < 4; ++j) {
            __hip_fp8_e4m3 q(v[j] * W_SCALE);
            lo |= ((unsigned int)q.__x) << (8 * j);
        }
        #pragma unroll
        for (int j = 0; j < 4; ++j) {
            __hip_fp8_e4m3 q(v[4 + j] * W_SCALE);
            hi |= ((unsigned int)q.__x) << (8 * j);
        }
        uint2 out; out.x = lo; out.y = hi;
        *(uint2*)(W8 + idx) = out;
    }
}

// K2: one wave per token, fp8 gathers (512 B/row -> 1 uint2 load per lane per row).
__global__ __launch_bounds__(256) void hs_loss_fp8_kernel(
    const float* __restrict__ h,
    const int*   __restrict__ targets,
    const unsigned char* __restrict__ W8,
    const int*   __restrict__ path_nodes,
    const float* __restrict__ path_targets,
    const float* __restrict__ path_masks,
    float* __restrict__ loss_part,
    float* __restrict__ cnt_part,
    int n, int vocab)
{
    const int tid  = threadIdx.x;
    const int wave = tid >> 6;
    const int lane = tid & 63;
    int token = blockIdx.x * 4 + wave;
    const bool alive = (token < n);
    if (!alive) token = n - 1;

    // lane covers h elements [lane*8, lane*8+8): matches fp8 byte layout
    const float4* h4 = (const float4*)(h + (size_t)token * DHID);
    float4 h0 = h4[lane * 2];
    float4 h1 = h4[lane * 2 + 1];

    int t = targets[token];
    t = min(max(t, 0), vocab - 1);
    t = __builtin_amdgcn_readfirstlane(t);   // force scalar path for node/tgt/mask loads

    int nodes[MAXP];
    #pragma unroll
    for (int s = 0; s < MAXP; ++s)
        nodes[s] = max(path_nodes[t * MAXP + s], 0);

    // issue all 18 row gathers (8 B/lane each) before consuming
    uint2 wq[MAXP];
    #pragma unroll
    for (int s = 0; s < MAXP; ++s)
        wq[s] = *(const uint2*)(W8 + (size_t)nodes[s] * DHID + lane * 8);

    float p[MAXP];
    #pragma unroll
    for (int s = 0; s < MAXP; ++s) {
        const unsigned int lo = wq[s].x, hi = wq[s].y;
        p[s] = fp8tof(lo)       * h0.x + fp8tof(lo >> 8)  * h0.y
             + fp8tof(lo >> 16) * h0.z + fp8tof(lo >> 24) * h0.w
             + fp8tof(hi)       * h1.x + fp8tof(hi >> 8)  * h1.y
             + fp8tof(hi >> 16) * h1.z + fp8tof(hi >> 24) * h1.w;
    }

    #pragma unroll
    for (int s = 0; s < MAXP; ++s) {
        #pragma unroll
        for (int off = 32; off > 0; off >>= 1)
            p[s] += __shfl_xor(p[s], off);
    }

    float contrib = 0.f, mval = 0.f;
    if (lane < MAXP) {
        float xs = 0.f;
        #pragma unroll
        for (int s = 0; s < MAXP; ++s)
            if (lane == s) xs = p[s];
        const float x   = xs * W_INV_SCALE;
        const float tgt = path_targets[t * MAXP + lane];
        const float msk = path_masks[t * MAXP + lane];
        const float bce = fmaxf(x, 0.f) - x * tgt + log1pf(expf(-fabsf(x)));
        contrib = bce * msk;
        mval    = msk;
    }
    #pragma unroll
    for (int off = 32; off > 0; off >>= 1) {
        contrib += __shfl_xor(contrib, off);
        mval    += __shfl_xor(mval, off);
    }

    __shared__ float ls[4], cs[4];
    if (lane == 0) {
        ls[wave] = alive ? contrib : 0.f;
        cs[wave] = (alive && mval > 0.f) ? 1.f : 0.f;
    }
    __syncthreads();
    if (tid == 0) {
        loss_part[blockIdx.x] = ls[0] + ls[1] + ls[2] + ls[3];
        cnt_part[blockIdx.x]  = cs[0] + cs[1] + cs[2] + cs[3];
    }
}

// Fallback (fp32 direct gathers) if workspace is too small for W8.
__global__ __launch_bounds__(256) void hs_loss_fp32_kernel(
    const float* __restrict__ h,
    const int*   __restrict__ targets,
    const float* __restrict__ W,
    const int*   __restrict__ path_nodes,
    const float* __restrict__ path_targets,
    const float* __restrict__ path_masks,
    float* __restrict__ loss_part,
    float* __restrict__ cnt_part,
    int n, int vocab)
{
    const int tid  = threadIdx.x;
    const int wave = tid >> 6;
    const int lane = tid & 63;
    int token = blockIdx.x * 4 + wave;
    const bool alive = (token < n);
    if (!alive) token = n - 1;

    const float4* h4 = (const float4*)(h + (size_t)token * DHID);
    float4 h0 = h4[lane];
    float4 h1 = h4[lane + 64];

    int t = targets[token];
    t = min(max(t, 0), vocab - 1);
    t = __builtin_amdgcn_readfirstlane(t);

    int nodes[MAXP];
    #pragma unroll
    for (int s = 0; s < MAXP; ++s)
        nodes[s] = max(path_nodes[t * MAXP + s], 0);

    float p[MAXP];
    #pragma unroll
    for (int g = 0; g < 3; ++g) {
        float4 w0[6], w1[6];
        #pragma unroll
        for (int j = 0; j < 6; ++j) {
            const float4* wr = (const float4*)(W + (size_t)nodes[g * 6 + j] * DHID);
            w0[j] = wr[lane];
            w1[j] = wr[lane + 64];
        }
        #pragma unroll
        for (int j = 0; j < 6; ++j) {
            p[g * 6 + j] = w0[j].x * h0.x + w0[j].y * h0.y + w0[j].z * h0.z + w0[j].w * h0.w
                         + w1[j].x * h1.x + w1[j].y * h1.y + w1[j].z * h1.z + w1[j].w * h1.w;
        }
    }

    #pragma unroll
    for (int s = 0; s < MAXP; ++s) {
        #pragma unroll
        for (int off = 32; off > 0; off >>= 1)
            p[s] += __shfl_xor(p[s], off);
    }

    float contrib = 0.f, mval = 0.f;
    if (lane < MAXP) {
        float x = 0.f;
        #pragma unroll
        for (int s = 0; s < MAXP; ++s)
            if (lane == s) x = p[s];
        const float tgt = path_targets[t * MAXP + lane];
        const float msk = path_masks[t * MAXP + lane];
        const float bce = fmaxf(x, 0.f) - x * tgt + log1pf(expf(-fabsf(x)));
        contrib = bce * msk;
        mval    = msk;
    }
    #pragma unroll
    for (int off = 32; off > 0; off >>= 1) {
        contrib += __shfl_xor(contrib, off);
        mval    += __shfl_xor(mval, off);
    }

    __shared__ float ls[4], cs[4];
    if (lane == 0) {
        ls[wave] = alive ? contrib : 0.f;
        cs[wave] = (alive && mval > 0.f) ? 1.f : 0.f;
    }
    __syncthreads();
    if (tid == 0) {
        loss_part[blockIdx.x] = ls[0] + ls[1] + ls[2] + ls[3];
        cnt_part[blockIdx.x]  = cs[0] + cs[1] + cs[2] + cs[3];
    }
}

__global__ __launch_bounds__(256) void hs_finalize_kernel(
    const float* __restrict__ loss_part,
    const float* __restrict__ cnt_part,
    float* __restrict__ out, int nblocks)
{
    __shared__ float sl[4], sc[4];
    float l = 0.f, c = 0.f;
    for (int i = threadIdx.x; i < nblocks; i += 256) {
        l += loss_part[i];
        c += cnt_part[i];
    }
    #pragma unroll
    for (int off = 32; off > 0; off >>= 1) {
        l += __shfl_xor(l, off);
        c += __shfl_xor(c, off);
    }
    const int wave = threadIdx.x >> 6;
    const int lane = threadIdx.x & 63;
    if (lane == 0) { sl[wave] = l; sc[wave] = c; }
    __syncthreads();
    if (threadIdx.x == 0) {
        const float L = sl[0] + sl[1] + sl[2] + sl[3];
        const float C = sc[0] + sc[1] + sc[2] + sc[3];
        out[0] = (C > 0.f) ? L / fmaxf(C, 1.f) : 0.f;
    }
}

extern "C" void kernel_launch(void* const* d_in, const int* in_sizes, int n_in,
                              void* d_out, int out_size, void* d_ws, size_t ws_size,
                              hipStream_t stream) {
    const float* h            = (const float*)d_in[0];
    const int*   targets      = (const int*)d_in[1];
    const float* W            = (const float*)d_in[2];
    const int*   path_nodes   = (const int*)d_in[3];
    const float* path_targets = (const float*)d_in[4];
    const float* path_masks   = (const float*)d_in[5];
    float*       out          = (float*)d_out;

    const int n          = in_sizes[1];           // tokens (B*S)
    const int vocab      = in_sizes[3] / MAXP;    // 50257
    const int n_internal = in_sizes[2] / DHID;    // 50256
    const int w_elems    = n_internal * DHID;

    const int nblocks = (n + 3) / 4;              // 4 tokens (waves) per block

    const size_t w8_bytes = (size_t)w_elems;
    const size_t part_off = (w8_bytes + 255) & ~(size_t)255;
    const size_t need     = part_off + (size_t)2 * nblocks * sizeof(float);

    if (ws_size >= need) {
        unsigned char* W8   = (unsigned char*)d_ws;
        float* loss_part    = (float*)((char*)d_ws + part_off);
        float* cnt_part     = loss_part + nblocks;

        convert_w_kernel<<<2048, 256, 0, stream>>>(W, W8, w_elems);
        hs_loss_fp8_kernel<<<nblocks, 256, 0, stream>>>(h, targets, W8, path_nodes,
                                                        path_targets, path_masks,
                                                        loss_part, cnt_part, n, vocab);
        hs_finalize_kernel<<<1, 256, 0, stream>>>(loss_part, cnt_part, out, nblocks);
    } else {
        float* loss_part = (float*)d_ws;
        float* cnt_part  = loss_part + nblocks;
        hs_loss_fp32_kernel<<<nblocks, 256, 0, stream>>>(h, targets, W, path_nodes,
                                                         path_targets, path_masks,
                                                         loss_part, cnt_part, n, vocab);
        hs_finalize_kernel<<<1, 256, 0, stream>>>(loss_part, cnt_part, out, nblocks);
    }
}